// Round 24
// baseline (46.430 us; speedup 1.0000x reference)
//
#include <hip/hip_runtime.h>
#include <hip/hip_bf16.h>

typedef __bf16 bf16x8 __attribute__((ext_vector_type(8)));
typedef __bf16 bf16x4 __attribute__((ext_vector_type(4)));
typedef float  f32x4  __attribute__((ext_vector_type(4)));
typedef float  flt4v  __attribute__((ext_vector_type(4)));
typedef int    int4v  __attribute__((ext_vector_type(4)));

#define ALPHA 0.2f
#define LOG2E 1.44269504089f
// B=8, N=2048, D=128. Inputs: h,W,a f32; adj int32. Output f32.
// Wh stored MFMA-B-fragment-native: T[b][jt(32)][kk(2)][ct(8)][lane(64)][u(8)] bf16.

// Kernel A: Wh + scores (round-17 structure; wvs/wvd split across all 256 threads).
__global__ __launch_bounds__(256) void gat_wh(
    const float* __restrict__ h,
    const float* __restrict__ W,
    const float* __restrict__ a,
    __bf16* __restrict__ T,                  // [8][262144] bf16 tiled Wh
    float* __restrict__ ssrc,                // [8*2048] (x log2e)
    float* __restrict__ sdst)                // [8*2048] (x log2e)
{
    __shared__ __bf16 Wt[128][136];
    __shared__ float wvs[128], wvd[128];
    const int tid = threadIdx.x;
    // W @ a_src / W @ a_dst: thread t<128 -> wvs[t], t>=128 -> wvd[t-128] (vectorized)
    {
        const int c = tid & 127;
        const float* wr = W + c * 128;
        const float* av = a + (tid >> 7) * 128;
        float s = 0.f;
        #pragma unroll
        for (int e = 0; e < 128; e += 4) {
            flt4v wv  = *reinterpret_cast<const flt4v*>(wr + e);
            flt4v av4 = *reinterpret_cast<const flt4v*>(av + e);
            s += wv[0] * av4[0] + wv[1] * av4[1] + wv[2] * av4[2] + wv[3] * av4[3];
        }
        if (tid < 128) wvs[c] = s; else wvd[c] = s;
    }
    #pragma unroll
    for (int it = 0; it < 8; ++it) {
        int o = (it * 256 + tid) * 8;
        flt4v v0 = *reinterpret_cast<const flt4v*>(W + o);
        flt4v v1 = *reinterpret_cast<const flt4v*>(W + o + 4);
        int d = o >> 7, e = o & 127;
        #pragma unroll
        for (int j = 0; j < 4; ++j) {
            Wt[e + j][d]     = (__bf16)v0[j];
            Wt[e + 4 + j][d] = (__bf16)v1[j];
        }
    }
    __syncthreads();
    const int wave = tid >> 6, lane = tid & 63;
    const int lr = lane & 15, lg = lane >> 4;
    const int row0 = blockIdx.x * 64 + wave * 16;
    f32x4 acc[8];
    #pragma unroll
    for (int ct = 0; ct < 8; ++ct) acc[ct] = (f32x4){0.f, 0.f, 0.f, 0.f};
    #pragma unroll
    for (int kk = 0; kk < 4; ++kk) {
        const float* hp = h + (size_t)(row0 + lr) * 128 + kk * 32 + lg * 8;
        flt4v h0 = *reinterpret_cast<const flt4v*>(hp);
        flt4v h1 = *reinterpret_cast<const flt4v*>(hp + 4);
        bf16x8 af;
        #pragma unroll
        for (int j = 0; j < 4; ++j) { af[j] = (__bf16)h0[j]; af[4 + j] = (__bf16)h1[j]; }
        #pragma unroll
        for (int ct = 0; ct < 8; ++ct) {
            bf16x8 bf_ = *reinterpret_cast<const bf16x8*>(&Wt[ct * 16 + lr][kk * 32 + lg * 8]);
            acc[ct] = __builtin_amdgcn_mfma_f32_16x16x32_bf16(af, bf_, acc[ct], 0, 0, 0);
        }
    }
    const int b  = row0 >> 11;
    const int n0 = row0 & 2047;
    __bf16* tb = T + (size_t)b * 262144;
    const int j0t = n0 + lg * 4;
    const int jt  = j0t >> 6;
    const int kk2 = (j0t >> 5) & 1;
    const int lgp = (j0t >> 3) & 3;
    const int u0  = j0t & 7;
    #pragma unroll
    for (int ct = 0; ct < 8; ++ct) {
        bf16x4 v;
        #pragma unroll
        for (int q = 0; q < 4; ++q) v[q] = (__bf16)acc[ct][q];
        *reinterpret_cast<bf16x4*>(tb + ((jt * 2 + kk2) * 8 + ct) * 512 + lgp * 128 + lr * 8 + u0) = v;
    }
    const float* hrow = h + (size_t)(row0 + lr) * 128 + lg * 32;
    float s0 = 0.f, s1 = 0.f;
    #pragma unroll
    for (int u = 0; u < 32; u += 4) {
        flt4v hv = *reinterpret_cast<const flt4v*>(hrow + u);
        #pragma unroll
        for (int q = 0; q < 4; ++q) {
            float x = hv[q];
            s0 += x * wvs[lg * 32 + u + q];
            s1 += x * wvd[lg * 32 + u + q];
        }
    }
    s0 += __shfl_xor(s0, 16, 64); s0 += __shfl_xor(s0, 32, 64);
    s1 += __shfl_xor(s1, 16, 64); s1 += __shfl_xor(s1, 32, 64);
    if (lg == 0) {
        ssrc[row0 + lr] = s0 * LOG2E;
        sdst[row0 + lr] = s1 * LOG2E;
    }
}

// Kernel C: round-21 ring + setprio (r23) + P-buffer XOR swizzle (byte ^= plgp<<4
// on BOTH write and read sides) to break the 16-way bank conflict on P-writes.
__global__ __launch_bounds__(512) void gat_attn(
    const int* __restrict__ adj,                // [8][2048][2048]
    const __bf16* __restrict__ T,               // [8][262144] bf16 tiled Wh
    const float* __restrict__ ssrc,             // x log2e
    const float* __restrict__ sdst,             // x log2e
    float* __restrict__ out)                    // [8][2048][128] f32
{
    __shared__ __bf16 Pl[4][8][512];            // 4-deep A-frag P ring (32 KB)
    __shared__ float  lsumf[32];
    __shared__ f32x4  mbuf[4][2][2][64];        // kk=1 partial accs (16 KB)

    const int tid = threadIdx.x, w = tid >> 6, l = tid & 63;
    const int lr = l & 15, lg = l >> 4;
    const int kkR = w >> 2, cp = w & 3;         // MFMA-role
    const int b  = blockIdx.x & 7;
    const int i0 = (blockIdx.x >> 3) << 5;

    // P-role geometry (identical to round 17/21)
    const int prow = 4 * w + (l >> 4);
    const int row  = i0 + prow;
    const int jc   = (l & 15) * 8;
    const int pt2  = (l & 15) >> 3;
    const int pkk  = ((l & 15) >> 2) & 1;
    const int plgp = (l & 15) & 3;
    const int pbuf = pt2 * 4 + (w >> 2) * 2 + pkk;
    const int pslot = (prow & 15) + plgp * 16;
    const int pbyte = (pslot * 16) ^ (plgp << 4);          // swizzled write byte
    const int rbyte = (l * 16) ^ ((l >> 4) << 4);          // swizzled read byte
    const float si = ssrc[b * 2048 + row];
    const int* arow = adj + ((size_t)b * 2048 + row) * 2048;
    const float* sd = sdst + b * 2048;
    const __bf16* tb = T + (size_t)b * 262144;

    f32x4 acc[2][2];
    #pragma unroll
    for (int g = 0; g < 2; ++g)
        #pragma unroll
        for (int c2 = 0; c2 < 2; ++c2) acc[g][c2] = (f32x4){0.f, 0.f, 0.f, 0.f};
    float lrow = 0.f;

    // ---- prologue: P(intervals 0 and 1) -> Pl[0], Pl[1] ----
    #pragma unroll
    for (int pv = 0; pv < 2; ++pv) {
        const int off = pv * 128 + jc;
        int4v a0 = *reinterpret_cast<const int4v*>(arow + off);
        int4v a1 = *reinterpret_cast<const int4v*>(arow + off + 4);
        flt4v s0 = *reinterpret_cast<const flt4v*>(sd + off);
        flt4v s1 = *reinterpret_cast<const flt4v*>(sd + off + 4);
        bf16x8 pw;
        #pragma unroll
        for (int u = 0; u < 4; ++u) {
            float e0 = si + s0[u], e1 = si + s1[u];
            e0 = fmaxf(e0, ALPHA * e0); e1 = fmaxf(e1, ALPHA * e1);
            float p0 = exp2f(e0), p1 = exp2f(e1);
            p0 = (a0[u] != 0) ? p0 : 0.f;
            p1 = (a1[u] != 0) ? p1 : 0.f;
            __bf16 pb0 = (__bf16)p0, pb1 = (__bf16)p1;
            lrow += (float)pb0 + (float)pb1;
            pw[u] = pb0; pw[4 + u] = pb1;
        }
        *reinterpret_cast<bf16x8*>(reinterpret_cast<char*>(&Pl[pv][pbuf][0]) + pbyte) = pw;
    }
    __syncthreads();

    // ---- main loop: barrier every SECOND interval (9 total) ----
    #pragma unroll 4
    for (int iv = 0; iv < 16; ++iv) {
        const int cur = iv & 3;
        const int wrt = (iv + 2) & 3;
        const int jt0 = iv * 2;
        // (1) interval iv+2 adj + sdst loads (issued early)
        int4v an0 = {0,0,0,0}, an1 = {0,0,0,0};
        flt4v sn0, sn1;
        if (iv < 14) {
            const int off = (iv + 2) * 128 + jc;
            an0 = *reinterpret_cast<const int4v*>(arow + off);
            an1 = *reinterpret_cast<const int4v*>(arow + off + 4);
            sn0 = *reinterpret_cast<const flt4v*>(sd + off);
            sn1 = *reinterpret_cast<const flt4v*>(sd + off + 4);
        }
        // (2) current B-frag global loads
        const __bf16* tk0 = tb + (size_t)(((jt0 * 2 + kkR) * 8) + cp * 2) * 512 + l * 8;
        const __bf16* tk1 = tb + (size_t)((((jt0 + 1) * 2 + kkR) * 8) + cp * 2) * 512 + l * 8;
        bf16x8 b00 = *reinterpret_cast<const bf16x8*>(tk0);
        bf16x8 b01 = *reinterpret_cast<const bf16x8*>(tk0 + 512);
        bf16x8 b10 = *reinterpret_cast<const bf16x8*>(tk1);
        bf16x8 b11 = *reinterpret_cast<const bf16x8*>(tk1 + 512);
        // (3) current A-frag LDS reads (swizzled)
        bf16x8 a00 = *reinterpret_cast<const bf16x8*>(reinterpret_cast<const char*>(&Pl[cur][0 + 0 + kkR][0]) + rbyte);
        bf16x8 a01 = *reinterpret_cast<const bf16x8*>(reinterpret_cast<const char*>(&Pl[cur][0 + 2 + kkR][0]) + rbyte);
        bf16x8 a10 = *reinterpret_cast<const bf16x8*>(reinterpret_cast<const char*>(&Pl[cur][4 + 0 + kkR][0]) + rbyte);
        bf16x8 a11 = *reinterpret_cast<const bf16x8*>(reinterpret_cast<const char*>(&Pl[cur][4 + 2 + kkR][0]) + rbyte);
        // (4) MFMAs (setprio boost)
        __builtin_amdgcn_s_setprio(1);
        acc[0][0] = __builtin_amdgcn_mfma_f32_16x16x32_bf16(a00, b00, acc[0][0], 0, 0, 0);
        acc[0][1] = __builtin_amdgcn_mfma_f32_16x16x32_bf16(a00, b01, acc[0][1], 0, 0, 0);
        acc[1][0] = __builtin_amdgcn_mfma_f32_16x16x32_bf16(a01, b00, acc[1][0], 0, 0, 0);
        acc[1][1] = __builtin_amdgcn_mfma_f32_16x16x32_bf16(a01, b01, acc[1][1], 0, 0, 0);
        acc[0][0] = __builtin_amdgcn_mfma_f32_16x16x32_bf16(a10, b10, acc[0][0], 0, 0, 0);
        acc[0][1] = __builtin_amdgcn_mfma_f32_16x16x32_bf16(a10, b11, acc[0][1], 0, 0, 0);
        acc[1][0] = __builtin_amdgcn_mfma_f32_16x16x32_bf16(a11, b10, acc[1][0], 0, 0, 0);
        acc[1][1] = __builtin_amdgcn_mfma_f32_16x16x32_bf16(a11, b11, acc[1][1], 0, 0, 0);
        __builtin_amdgcn_s_setprio(0);
        // (5) exp + ds_write P(iv+2) into ring slot wrt (swizzled)
        if (iv < 14) {
            bf16x8 pw;
            #pragma unroll
            for (int u = 0; u < 4; ++u) {
                float e0 = si + sn0[u], e1 = si + sn1[u];
                e0 = fmaxf(e0, ALPHA * e0); e1 = fmaxf(e1, ALPHA * e1);
                float p0 = exp2f(e0), p1 = exp2f(e1);
                p0 = (an0[u] != 0) ? p0 : 0.f;
                p1 = (an1[u] != 0) ? p1 : 0.f;
                __bf16 pb0 = (__bf16)p0, pb1 = (__bf16)p1;
                lrow += (float)pb0 + (float)pb1;
                pw[u] = pb0; pw[4 + u] = pb1;
            }
            *reinterpret_cast<bf16x8*>(reinterpret_cast<char*>(&Pl[wrt][pbuf][0]) + pbyte) = pw;
        }
        // (6) barrier at the end of each pair
        if (iv & 1) __syncthreads();
    }

    // denominators: each row owned by one 16-lane group
    lrow += __shfl_xor(lrow, 1, 64);
    lrow += __shfl_xor(lrow, 2, 64);
    lrow += __shfl_xor(lrow, 4, 64);
    lrow += __shfl_xor(lrow, 8, 64);
    if ((l & 15) == 0) lsumf[prow] = lrow;
    // kk=1 waves publish their partial accumulators
    if (kkR == 1) {
        #pragma unroll
        for (int g = 0; g < 2; ++g)
            #pragma unroll
            for (int c2 = 0; c2 < 2; ++c2)
                mbuf[cp][g][c2][l] = acc[g][c2];
    }
    __syncthreads();
    // kk=0 waves merge + write output
    if (kkR == 0) {
        #pragma unroll
        for (int g = 0; g < 2; ++g) {
            float den[4];
            #pragma unroll
            for (int q = 0; q < 4; ++q) den[q] = lsumf[g * 16 + lg * 4 + q];
            #pragma unroll
            for (int c2 = 0; c2 < 2; ++c2) {
                f32x4 av = acc[g][c2];
                f32x4 mv = mbuf[cp][g][c2][l];
                const int col = (cp * 2 + c2) * 16 + lr;
                #pragma unroll
                for (int q = 0; q < 4; ++q) {
                    const int orow = i0 + g * 16 + lg * 4 + q;
                    out[((size_t)b * 2048 + orow) * 128 + col] = (av[q] + mv[q]) / den[q];
                }
            }
        }
    }
}

extern "C" void kernel_launch(void* const* d_in, const int* in_sizes, int n_in,
                              void* d_out, int out_size, void* d_ws, size_t ws_size,
                              hipStream_t stream)
{
    const float* h = nullptr; const int* adj = nullptr;
    const float* W = nullptr; const float* a = nullptr;
    for (int i = 0; i < n_in; ++i) {
        switch (in_sizes[i]) {
            case 2097152:  h   = (const float*)d_in[i]; break;
            case 33554432: adj = (const int*)d_in[i];   break;
            case 16384:    W   = (const float*)d_in[i]; break;
            case 256:      a   = (const float*)d_in[i]; break;
        }
    }
    if (!h || !adj || !W || !a) {
        h   = (const float*)d_in[0];
        adj = (const int*)d_in[1];
        W   = (const float*)d_in[2];
        a   = (const float*)d_in[3];
    }

    __bf16* T = (__bf16*)d_ws;                                        // 4 MB
    float* ssrc = (float*)((char*)d_ws + (size_t)4 * 1024 * 1024);    // 64 KB
    float* sdst = ssrc + 8 * 2048;                                    // 64 KB

    gat_wh<<<256, 256, 0, stream>>>(h, W, a, T, ssrc, sdst);
    gat_attn<<<512, 512, 0, stream>>>(adj, T, ssrc, sdst, (float*)d_out);
}

// Round 25
// 44.060 us; speedup vs baseline: 1.0538x; 1.0538x over previous
//
#include <hip/hip_runtime.h>
#include <hip/hip_bf16.h>

typedef __bf16 bf16x8 __attribute__((ext_vector_type(8)));
typedef __bf16 bf16x4 __attribute__((ext_vector_type(4)));
typedef float  f32x4  __attribute__((ext_vector_type(4)));
typedef float  flt4v  __attribute__((ext_vector_type(4)));
typedef int    int4v  __attribute__((ext_vector_type(4)));

#define ALPHA 0.2f
#define LOG2E 1.44269504089f
// B=8, N=2048, D=128. Inputs: h,W,a f32; adj int32. Output f32.
// Wh stored MFMA-B-fragment-native: T[b][jt(32)][kk(2)][ct(8)][lane(64)][u(8)] bf16.

// Kernel A: Wh + scores (byte-exact round-17 version: 256 blocks x 64 rows).
__global__ __launch_bounds__(256) void gat_wh(
    const float* __restrict__ h,
    const float* __restrict__ W,
    const float* __restrict__ a,
    __bf16* __restrict__ T,                  // [8][262144] bf16 tiled Wh
    float* __restrict__ ssrc,                // [8*2048] (x log2e)
    float* __restrict__ sdst)                // [8*2048] (x log2e)
{
    __shared__ __bf16 Wt[128][136];
    __shared__ float wvs[128], wvd[128];
    const int tid = threadIdx.x;
    if (tid < 128) {
        float s0 = 0.f, s1 = 0.f;
        const float* wr = W + tid * 128;
        #pragma unroll 4
        for (int e = 0; e < 128; ++e) {
            float w = wr[e];
            s0 += w * a[e];
            s1 += w * a[128 + e];
        }
        wvs[tid] = s0; wvd[tid] = s1;
    }
    #pragma unroll
    for (int it = 0; it < 8; ++it) {
        int o = (it * 256 + tid) * 8;
        flt4v v0 = *reinterpret_cast<const flt4v*>(W + o);
        flt4v v1 = *reinterpret_cast<const flt4v*>(W + o + 4);
        int d = o >> 7, e = o & 127;
        #pragma unroll
        for (int j = 0; j < 4; ++j) {
            Wt[e + j][d]     = (__bf16)v0[j];
            Wt[e + 4 + j][d] = (__bf16)v1[j];
        }
    }
    __syncthreads();
    const int wave = tid >> 6, lane = tid & 63;
    const int lr = lane & 15, lg = lane >> 4;
    const int row0 = blockIdx.x * 64 + wave * 16;
    f32x4 acc[8];
    #pragma unroll
    for (int ct = 0; ct < 8; ++ct) acc[ct] = (f32x4){0.f, 0.f, 0.f, 0.f};
    #pragma unroll
    for (int kk = 0; kk < 4; ++kk) {
        const float* hp = h + (size_t)(row0 + lr) * 128 + kk * 32 + lg * 8;
        flt4v h0 = *reinterpret_cast<const flt4v*>(hp);
        flt4v h1 = *reinterpret_cast<const flt4v*>(hp + 4);
        bf16x8 af;
        #pragma unroll
        for (int j = 0; j < 4; ++j) { af[j] = (__bf16)h0[j]; af[4 + j] = (__bf16)h1[j]; }
        #pragma unroll
        for (int ct = 0; ct < 8; ++ct) {
            bf16x8 bf_ = *reinterpret_cast<const bf16x8*>(&Wt[ct * 16 + lr][kk * 32 + lg * 8]);
            acc[ct] = __builtin_amdgcn_mfma_f32_16x16x32_bf16(af, bf_, acc[ct], 0, 0, 0);
        }
    }
    const int b  = row0 >> 11;
    const int n0 = row0 & 2047;
    __bf16* tb = T + (size_t)b * 262144;
    const int j0t = n0 + lg * 4;
    const int jt  = j0t >> 6;
    const int kk2 = (j0t >> 5) & 1;
    const int lgp = (j0t >> 3) & 3;
    const int u0  = j0t & 7;
    #pragma unroll
    for (int ct = 0; ct < 8; ++ct) {
        bf16x4 v;
        #pragma unroll
        for (int q = 0; q < 4; ++q) v[q] = (__bf16)acc[ct][q];
        *reinterpret_cast<bf16x4*>(tb + ((jt * 2 + kk2) * 8 + ct) * 512 + lgp * 128 + lr * 8 + u0) = v;
    }
    const float* hrow = h + (size_t)(row0 + lr) * 128 + lg * 32;
    float s0 = 0.f, s1 = 0.f;
    #pragma unroll
    for (int u = 0; u < 32; u += 4) {
        flt4v hv = *reinterpret_cast<const flt4v*>(hrow + u);
        #pragma unroll
        for (int q = 0; q < 4; ++q) {
            float x = hv[q];
            s0 += x * wvs[lg * 32 + u + q];
            s1 += x * wvd[lg * 32 + u + q];
        }
    }
    s0 += __shfl_xor(s0, 16, 64); s0 += __shfl_xor(s0, 32, 64);
    s1 += __shfl_xor(s1, 16, 64); s1 += __shfl_xor(s1, 32, 64);
    if (lg == 0) {
        ssrc[row0 + lr] = s0 * LOG2E;
        sdst[row0 + lr] = s1 * LOG2E;
    }
}

// Kernel C: byte-exact round-21 ring structure (4-deep Pl ring, barrier every
// 2nd interval, write distance 2) + s_setprio(1) around the MFMA cluster (T5).
__global__ __launch_bounds__(512) void gat_attn(
    const int* __restrict__ adj,                // [8][2048][2048]
    const __bf16* __restrict__ T,               // [8][262144] bf16 tiled Wh
    const float* __restrict__ ssrc,             // x log2e
    const float* __restrict__ sdst,             // x log2e
    float* __restrict__ out)                    // [8][2048][128] f32
{
    __shared__ __bf16 Pl[4][8][512];            // 4-deep A-frag P ring (32 KB)
    __shared__ float  lsumf[32];
    __shared__ f32x4  mbuf[4][2][2][64];        // kk=1 partial accs (16 KB)

    const int tid = threadIdx.x, w = tid >> 6, l = tid & 63;
    const int lr = l & 15, lg = l >> 4;
    const int kkR = w >> 2, cp = w & 3;         // MFMA-role
    const int b  = blockIdx.x & 7;
    const int i0 = (blockIdx.x >> 3) << 5;

    // P-role geometry (identical to round 17/21)
    const int prow = 4 * w + (l >> 4);
    const int row  = i0 + prow;
    const int jc   = (l & 15) * 8;
    const int pt2  = (l & 15) >> 3;
    const int pkk  = ((l & 15) >> 2) & 1;
    const int plgp = (l & 15) & 3;
    const int pbuf = pt2 * 4 + (w >> 2) * 2 + pkk;
    const int pslot = (prow & 15) + plgp * 16;
    const float si = ssrc[b * 2048 + row];
    const int* arow = adj + ((size_t)b * 2048 + row) * 2048;
    const float* sd = sdst + b * 2048;
    const __bf16* tb = T + (size_t)b * 262144;

    f32x4 acc[2][2];
    #pragma unroll
    for (int g = 0; g < 2; ++g)
        #pragma unroll
        for (int c2 = 0; c2 < 2; ++c2) acc[g][c2] = (f32x4){0.f, 0.f, 0.f, 0.f};
    float lrow = 0.f;

    // ---- prologue: P(intervals 0 and 1) -> Pl[0], Pl[1] ----
    #pragma unroll
    for (int pv = 0; pv < 2; ++pv) {
        const int off = pv * 128 + jc;
        int4v a0 = *reinterpret_cast<const int4v*>(arow + off);
        int4v a1 = *reinterpret_cast<const int4v*>(arow + off + 4);
        flt4v s0 = *reinterpret_cast<const flt4v*>(sd + off);
        flt4v s1 = *reinterpret_cast<const flt4v*>(sd + off + 4);
        bf16x8 pw;
        #pragma unroll
        for (int u = 0; u < 4; ++u) {
            float e0 = si + s0[u], e1 = si + s1[u];
            e0 = fmaxf(e0, ALPHA * e0); e1 = fmaxf(e1, ALPHA * e1);
            float p0 = exp2f(e0), p1 = exp2f(e1);
            p0 = (a0[u] != 0) ? p0 : 0.f;
            p1 = (a1[u] != 0) ? p1 : 0.f;
            __bf16 pb0 = (__bf16)p0, pb1 = (__bf16)p1;
            lrow += (float)pb0 + (float)pb1;
            pw[u] = pb0; pw[4 + u] = pb1;
        }
        *reinterpret_cast<bf16x8*>(&Pl[pv][pbuf][pslot * 8]) = pw;
    }
    __syncthreads();

    // ---- main loop: barrier every SECOND interval (9 total) ----
    #pragma unroll 4
    for (int iv = 0; iv < 16; ++iv) {
        const int cur = iv & 3;
        const int wrt = (iv + 2) & 3;
        const int jt0 = iv * 2;
        // (1) interval iv+2 adj + sdst loads (issued early)
        int4v an0 = {0,0,0,0}, an1 = {0,0,0,0};
        flt4v sn0, sn1;
        if (iv < 14) {
            const int off = (iv + 2) * 128 + jc;
            an0 = *reinterpret_cast<const int4v*>(arow + off);
            an1 = *reinterpret_cast<const int4v*>(arow + off + 4);
            sn0 = *reinterpret_cast<const flt4v*>(sd + off);
            sn1 = *reinterpret_cast<const flt4v*>(sd + off + 4);
        }
        // (2) current B-frag global loads
        const __bf16* tk0 = tb + (size_t)(((jt0 * 2 + kkR) * 8) + cp * 2) * 512 + l * 8;
        const __bf16* tk1 = tb + (size_t)((((jt0 + 1) * 2 + kkR) * 8) + cp * 2) * 512 + l * 8;
        bf16x8 b00 = *reinterpret_cast<const bf16x8*>(tk0);
        bf16x8 b01 = *reinterpret_cast<const bf16x8*>(tk0 + 512);
        bf16x8 b10 = *reinterpret_cast<const bf16x8*>(tk1);
        bf16x8 b11 = *reinterpret_cast<const bf16x8*>(tk1 + 512);
        // (3) current A-frag LDS reads
        bf16x8 a00 = *reinterpret_cast<const bf16x8*>(&Pl[cur][0 + 0 + kkR][l * 8]);
        bf16x8 a01 = *reinterpret_cast<const bf16x8*>(&Pl[cur][0 + 2 + kkR][l * 8]);
        bf16x8 a10 = *reinterpret_cast<const bf16x8*>(&Pl[cur][4 + 0 + kkR][l * 8]);
        bf16x8 a11 = *reinterpret_cast<const bf16x8*>(&Pl[cur][4 + 2 + kkR][l * 8]);
        // (4) MFMAs (setprio boost: keep matrix pipe fed while other waves load)
        __builtin_amdgcn_s_setprio(1);
        acc[0][0] = __builtin_amdgcn_mfma_f32_16x16x32_bf16(a00, b00, acc[0][0], 0, 0, 0);
        acc[0][1] = __builtin_amdgcn_mfma_f32_16x16x32_bf16(a00, b01, acc[0][1], 0, 0, 0);
        acc[1][0] = __builtin_amdgcn_mfma_f32_16x16x32_bf16(a01, b00, acc[1][0], 0, 0, 0);
        acc[1][1] = __builtin_amdgcn_mfma_f32_16x16x32_bf16(a01, b01, acc[1][1], 0, 0, 0);
        acc[0][0] = __builtin_amdgcn_mfma_f32_16x16x32_bf16(a10, b10, acc[0][0], 0, 0, 0);
        acc[0][1] = __builtin_amdgcn_mfma_f32_16x16x32_bf16(a10, b11, acc[0][1], 0, 0, 0);
        acc[1][0] = __builtin_amdgcn_mfma_f32_16x16x32_bf16(a11, b10, acc[1][0], 0, 0, 0);
        acc[1][1] = __builtin_amdgcn_mfma_f32_16x16x32_bf16(a11, b11, acc[1][1], 0, 0, 0);
        __builtin_amdgcn_s_setprio(0);
        // (5) exp + ds_write P(iv+2) into ring slot wrt
        if (iv < 14) {
            bf16x8 pw;
            #pragma unroll
            for (int u = 0; u < 4; ++u) {
                float e0 = si + sn0[u], e1 = si + sn1[u];
                e0 = fmaxf(e0, ALPHA * e0); e1 = fmaxf(e1, ALPHA * e1);
                float p0 = exp2f(e0), p1 = exp2f(e1);
                p0 = (an0[u] != 0) ? p0 : 0.f;
                p1 = (an1[u] != 0) ? p1 : 0.f;
                __bf16 pb0 = (__bf16)p0, pb1 = (__bf16)p1;
                lrow += (float)pb0 + (float)pb1;
                pw[u] = pb0; pw[4 + u] = pb1;
            }
            *reinterpret_cast<bf16x8*>(&Pl[wrt][pbuf][pslot * 8]) = pw;
        }
        // (6) barrier at the end of each pair
        if (iv & 1) __syncthreads();
    }

    // denominators: each row owned by one 16-lane group
    lrow += __shfl_xor(lrow, 1, 64);
    lrow += __shfl_xor(lrow, 2, 64);
    lrow += __shfl_xor(lrow, 4, 64);
    lrow += __shfl_xor(lrow, 8, 64);
    if ((l & 15) == 0) lsumf[prow] = lrow;
    // kk=1 waves publish their partial accumulators
    if (kkR == 1) {
        #pragma unroll
        for (int g = 0; g < 2; ++g)
            #pragma unroll
            for (int c2 = 0; c2 < 2; ++c2)
                mbuf[cp][g][c2][l] = acc[g][c2];
    }
    __syncthreads();
    // kk=0 waves merge + write output
    if (kkR == 0) {
        #pragma unroll
        for (int g = 0; g < 2; ++g) {
            float den[4];
            #pragma unroll
            for (int q = 0; q < 4; ++q) den[q] = lsumf[g * 16 + lg * 4 + q];
            #pragma unroll
            for (int c2 = 0; c2 < 2; ++c2) {
                f32x4 av = acc[g][c2];
                f32x4 mv = mbuf[cp][g][c2][l];
                const int col = (cp * 2 + c2) * 16 + lr;
                #pragma unroll
                for (int q = 0; q < 4; ++q) {
                    const int orow = i0 + g * 16 + lg * 4 + q;
                    out[((size_t)b * 2048 + orow) * 128 + col] = (av[q] + mv[q]) / den[q];
                }
            }
        }
    }
}

extern "C" void kernel_launch(void* const* d_in, const int* in_sizes, int n_in,
                              void* d_out, int out_size, void* d_ws, size_t ws_size,
                              hipStream_t stream)
{
    const float* h = nullptr; const int* adj = nullptr;
    const float* W = nullptr; const float* a = nullptr;
    for (int i = 0; i < n_in; ++i) {
        switch (in_sizes[i]) {
            case 2097152:  h   = (const float*)d_in[i]; break;
            case 33554432: adj = (const int*)d_in[i];   break;
            case 16384:    W   = (const float*)d_in[i]; break;
            case 256:      a   = (const float*)d_in[i]; break;
        }
    }
    if (!h || !adj || !W || !a) {
        h   = (const float*)d_in[0];
        adj = (const int*)d_in[1];
        W   = (const float*)d_in[2];
        a   = (const float*)d_in[3];
    }

    __bf16* T = (__bf16*)d_ws;                                        // 4 MB
    float* ssrc = (float*)((char*)d_ws + (size_t)4 * 1024 * 1024);    // 64 KB
    float* sdst = ssrc + 8 * 2048;                                    // 64 KB

    gat_wh<<<256, 256, 0, stream>>>(h, W, a, T, ssrc, sdst);
    gat_attn<<<512, 512, 0, stream>>>(adj, T, ssrc, sdst, (float*)d_out);
}